// Round 1
// baseline (107.857 us; speedup 1.0000x reference)
//
#include <hip/hip_runtime.h>
#include <math.h>

// AttnPool: score = h@W + b  -> per-segment softmax (segments = sorted batch ids)
//           out[b] = sum_i softmax_w[i] * h[i]   for i in segment b.
// One 64-lane wave per segment; segment range via binary search on sorted batch.
// Online-softmax chunking keeps it correct for any segment length.

constexpr int D = 128;
constexpr int CHUNK = 1024;   // rows of scores buffered in LDS per pass

__global__ __launch_bounds__(64) void attnpool_kernel(
    const float* __restrict__ h,
    const int*   __restrict__ batch,
    const float* __restrict__ W,
    const float* __restrict__ bias,
    float*       __restrict__ out,
    int N)
{
    const int seg  = blockIdx.x;
    const int lane = threadIdx.x;

    __shared__ float sW[D];
    __shared__ float sScore[CHUNK];

    sW[lane]      = W[lane];
    sW[lane + 64] = W[lane + 64];
    const float bconst = bias[0];

    // s = lower_bound(batch, seg); e = lower_bound(batch, seg+1)
    int lo = 0, hi = N;
    while (lo < hi) { int mid = (lo + hi) >> 1; if (batch[mid] <  seg) lo = mid + 1; else hi = mid; }
    const int s = lo;
    hi = N;
    while (lo < hi) { int mid = (lo + hi) >> 1; if (batch[mid] <= seg) lo = mid + 1; else hi = mid; }
    const int e = lo;
    const int len = e - s;

    float2* o2 = (float2*)(out + (size_t)seg * D);
    if (len <= 0) {              // empty segment: segment_sum of nothing = 0
        o2[lane] = make_float2(0.f, 0.f);
        return;
    }

    __syncthreads();             // sW ready (single wave, but keep it safe)

    float m = -INFINITY;         // running max
    float l = 0.f;               // running exp-sum
    float acc0 = 0.f, acc1 = 0.f;// unnormalized weighted feature sums (this lane's 2 dims)

    for (int cs = 0; cs < len; cs += CHUNK) {
        const int ce = min(len, cs + CHUNK);

        // ---- Phase A: scores for rows [cs, ce); lane-per-row serial dot ----
        float lmax = -INFINITY;
        for (int r = cs + lane; r < ce; r += 64) {
            const float4* hr = (const float4*)(h + (size_t)(s + r) * D);
            float d0 = 0.f, d1 = 0.f, d2 = 0.f, d3 = 0.f;
            #pragma unroll
            for (int q = 0; q < 32; q += 4) {
                float4 v0 = hr[q + 0], v1 = hr[q + 1], v2 = hr[q + 2], v3 = hr[q + 3];
                d0 = fmaf(v0.x, sW[4*q + 0], d0);  d0 = fmaf(v0.y, sW[4*q + 1], d0);
                d0 = fmaf(v0.z, sW[4*q + 2], d0);  d0 = fmaf(v0.w, sW[4*q + 3], d0);
                d1 = fmaf(v1.x, sW[4*q + 4], d1);  d1 = fmaf(v1.y, sW[4*q + 5], d1);
                d1 = fmaf(v1.z, sW[4*q + 6], d1);  d1 = fmaf(v1.w, sW[4*q + 7], d1);
                d2 = fmaf(v2.x, sW[4*q + 8], d2);  d2 = fmaf(v2.y, sW[4*q + 9], d2);
                d2 = fmaf(v2.z, sW[4*q +10], d2);  d2 = fmaf(v2.w, sW[4*q +11], d2);
                d3 = fmaf(v3.x, sW[4*q +12], d3);  d3 = fmaf(v3.y, sW[4*q +13], d3);
                d3 = fmaf(v3.z, sW[4*q +14], d3);  d3 = fmaf(v3.w, sW[4*q +15], d3);
            }
            const float sc = (d0 + d1) + (d2 + d3) + bconst;
            sScore[r - cs] = sc;
            lmax = fmaxf(lmax, sc);
        }
        __syncthreads();

        // ---- Phase B: wave reductions, online rescale ----
        #pragma unroll
        for (int o = 32; o > 0; o >>= 1) lmax = fmaxf(lmax, __shfl_xor(lmax, o));
        const float mnew  = fmaxf(m, lmax);
        const float scale = __expf(m - mnew);   // 0 when m == -inf (first chunk)

        float ls = 0.f;
        for (int r = cs + lane; r < ce; r += 64) {
            const float eq = __expf(sScore[r - cs] - mnew);
            sScore[r - cs] = eq;
            ls += eq;
        }
        #pragma unroll
        for (int o = 32; o > 0; o >>= 1) ls += __shfl_xor(ls, o);

        l = l * scale + ls;
        acc0 *= scale; acc1 *= scale;
        __syncthreads();

        // ---- Phase C: lanes cover feature dims; serial coalesced row walk ----
        const float* hb = h + (size_t)s * D + 2 * lane;
        #pragma unroll 4
        for (int r = cs; r < ce; ++r) {
            const float  w  = sScore[r - cs];                 // LDS broadcast read
            const float2 hv = *(const float2*)(hb + (size_t)r * D);
            acc0 = fmaf(hv.x, w, acc0);
            acc1 = fmaf(hv.y, w, acc1);
        }
        m = mnew;
        __syncthreads();
    }

    const float inv = 1.f / l;   // len>0 => l >= exp(0) contribution > 0
    o2[lane] = make_float2(acc0 * inv, acc1 * inv);
}

extern "C" void kernel_launch(void* const* d_in, const int* in_sizes, int n_in,
                              void* d_out, int out_size, void* d_ws, size_t ws_size,
                              hipStream_t stream) {
    const float* h     = (const float*)d_in[0];
    const int*   batch = (const int*)  d_in[1];
    const float* W     = (const float*)d_in[2];
    const float* bias  = (const float*)d_in[3];
    float*       out   = (float*)d_out;

    const int N = in_sizes[0] / D;   // 500000
    const int B = out_size / D;      // 10000

    attnpool_kernel<<<B, 64, 0, stream>>>(h, batch, W, bias, out, N);
}

// Round 2
// 100.163 us; speedup vs baseline: 1.0768x; 1.0768x over previous
//
#include <hip/hip_runtime.h>
#include <math.h>

// AttnPool: score = h@W + b -> per-segment softmax (segments = sorted batch ids)
//           out[b] = sum_i softmax_w[i] * h[i]  for rows i in segment b.
//
// Kernel 0 precomputes segment boundaries (batch is sorted) into d_ws.
// Main kernel: one 64-lane wave per segment, 4 independent waves per block.
// Scores live in registers (2 regs cover len<=128; online-softmax chunks for
// longer); phase C broadcasts them via __shfl. No block barriers in main path.

constexpr int D = 128;
constexpr int SEG_PER_BLOCK = 4;

// seg_start[t] = first row index i with batch[i] >= t, for t in [0, B].
__global__ void seg_bounds_kernel(const int* __restrict__ batch,
                                  int* __restrict__ seg_start, int N, int B) {
    int i = blockIdx.x * blockDim.x + threadIdx.x;
    if (i >= N) return;
    int b    = batch[i];
    int prev = (i == 0) ? -1 : batch[i - 1];
    for (int t = prev + 1; t <= b; ++t) seg_start[t] = i;
    if (i == N - 1) {
        for (int t = b + 1; t <= B; ++t) seg_start[t] = N;
    }
}

__device__ __forceinline__ float dotrow(const float* __restrict__ hp,
                                        const float* __restrict__ sW) {
    const float4* hr = (const float4*)hp;
    float d0 = 0.f, d1 = 0.f;
    #pragma unroll 8
    for (int q = 0; q < 32; q += 2) {
        float4 a = hr[q], b = hr[q + 1];
        d0 = fmaf(a.w, sW[4*q+3], fmaf(a.z, sW[4*q+2], fmaf(a.y, sW[4*q+1], fmaf(a.x, sW[4*q+0], d0))));
        d1 = fmaf(b.w, sW[4*q+7], fmaf(b.z, sW[4*q+6], fmaf(b.y, sW[4*q+5], fmaf(b.x, sW[4*q+4], d1))));
    }
    return d0 + d1;
}

template<bool USE_BOUNDS>
__global__ __launch_bounds__(256) void attnpool_kernel(
    const float* __restrict__ h,
    const int*   __restrict__ batch,
    const float* __restrict__ W,
    const float* __restrict__ bias,
    const int*   __restrict__ seg_start,
    float*       __restrict__ out,
    int N, int B)
{
    __shared__ float sW[D];
    const int tid = threadIdx.x;
    if (tid < D) sW[tid] = W[tid];
    __syncthreads();                       // only barrier; before any returns

    const int wave = tid >> 6;
    const int lane = tid & 63;
    const int seg  = blockIdx.x * SEG_PER_BLOCK + wave;
    if (seg >= B) return;

    int s, e;
    if (USE_BOUNDS) {
        s = seg_start[seg];
        e = seg_start[seg + 1];
    } else {
        int lo = 0, hi = N;
        while (lo < hi) { int mid = (lo + hi) >> 1; if (batch[mid] <  seg) lo = mid + 1; else hi = mid; }
        s = lo; hi = N;
        while (lo < hi) { int mid = (lo + hi) >> 1; if (batch[mid] <= seg) lo = mid + 1; else hi = mid; }
        e = lo;
    }
    const int len = e - s;

    float2* o2 = (float2*)(out + (size_t)seg * D);
    if (len <= 0) { o2[lane] = make_float2(0.f, 0.f); return; }

    const float bconst = bias[0];
    float m = -INFINITY, l = 0.f;
    float acc0 = 0.f, acc1 = 0.f;          // this lane's dims 2*lane, 2*lane+1

    for (int base = 0; base < len; base += 128) {
        const int cnt = min(len - base, 128);

        // ---- scores for rows base+lane and base+64+lane (registers) ----
        float sc0 = -INFINITY, sc1 = -INFINITY;
        int r0 = base + lane;
        if (r0 < len)      sc0 = dotrow(h + (size_t)(s + r0) * D, sW) + bconst;
        int r1 = base + 64 + lane;
        if (r1 < len)      sc1 = dotrow(h + (size_t)(s + r1) * D, sW) + bconst;

        // ---- wave max + online rescale ----
        float lm = fmaxf(sc0, sc1);
        #pragma unroll
        for (int o = 32; o > 0; o >>= 1) lm = fmaxf(lm, __shfl_xor(lm, o));
        const float mnew  = fmaxf(m, lm);          // finite: chunk has >=1 row
        const float scale = __expf(m - mnew);      // 0 on first chunk

        const float e0 = __expf(sc0 - mnew);       // exp(-inf)=0 for invalid rows
        const float e1 = __expf(sc1 - mnew);
        float ls = e0 + e1;
        #pragma unroll
        for (int o = 32; o > 0; o >>= 1) ls += __shfl_xor(ls, o);

        l = l * scale + ls;
        acc0 *= scale; acc1 *= scale;

        // ---- weighted feature sum: lanes cover dims, serial row walk ----
        const float* hb = h + (size_t)(s + base) * D + 2 * lane;
        #pragma unroll 4
        for (int r = 0; r < cnt; ++r) {
            const float wr = (r < 64) ? __shfl(e0, r) : __shfl(e1, r - 64);
            const float2 hv = *(const float2*)(hb + (size_t)r * D);
            acc0 = fmaf(hv.x, wr, acc0);
            acc1 = fmaf(hv.y, wr, acc1);
        }
        m = mnew;
    }

    const float inv = 1.f / l;
    o2[lane] = make_float2(acc0 * inv, acc1 * inv);
}

extern "C" void kernel_launch(void* const* d_in, const int* in_sizes, int n_in,
                              void* d_out, int out_size, void* d_ws, size_t ws_size,
                              hipStream_t stream) {
    const float* h     = (const float*)d_in[0];
    const int*   batch = (const int*)  d_in[1];
    const float* W     = (const float*)d_in[2];
    const float* bias  = (const float*)d_in[3];
    float*       out   = (float*)d_out;

    const int N = in_sizes[0] / D;   // 500000
    const int B = out_size / D;      // 10000

    const int grid = (B + SEG_PER_BLOCK - 1) / SEG_PER_BLOCK;

    if (ws_size >= (size_t)(B + 1) * sizeof(int)) {
        int* seg_start = (int*)d_ws;
        seg_bounds_kernel<<<(N + 255) / 256, 256, 0, stream>>>(batch, seg_start, N, B);
        attnpool_kernel<true><<<grid, 256, 0, stream>>>(h, batch, W, bias, seg_start, out, N, B);
    } else {
        attnpool_kernel<false><<<grid, 256, 0, stream>>>(h, batch, W, bias, nullptr, out, N, B);
    }
}

// Round 3
// 49.958 us; speedup vs baseline: 2.1590x; 2.0050x over previous
//
#include <hip/hip_runtime.h>
#include <math.h>

// AttnPool: score = h@W + b -> per-segment softmax (segments = sorted batch ids)
//           out[b] = sum_i softmax_w[i] * h[i]  for rows i in segment b.
//
// Single pass over h, fully coalesced, register-resident:
//   - one 64-lane wave per segment (4 waves/block), bounds from seg_start[].
//   - chunk of 8 rows: load i covers row-pair (2i, 2i+1): lanes 0-31 read
//     dims 4l..4l+3 of row 2i, lanes 32-63 of row 2i+1 -> one contiguous
//     1KB block per instruction.
//   - scores: per-lane 4-dim partial dot + 5-step __shfl_xor butterfly
//     within each 32-lane half; online softmax; accumulate from the SAME
//     registers (h is read exactly once).
//   - explicit A/B register ping-pong keeps next chunk's loads in flight.

constexpr int D = 128;
constexpr int SEG_PER_BLOCK = 4;

// seg_start[t] = first row index i with batch[i] >= t, for t in [0, B].
__global__ void seg_bounds_kernel(const int* __restrict__ batch,
                                  int* __restrict__ seg_start, int N, int B) {
    int i = blockIdx.x * blockDim.x + threadIdx.x;
    if (i >= N) return;
    int b    = batch[i];
    int prev = (i == 0) ? -1 : batch[i - 1];
    for (int t = prev + 1; t <= b; ++t) seg_start[t] = i;
    if (i == N - 1) {
        for (int t = b + 1; t <= B; ++t) seg_start[t] = N;
    }
}

template<bool USE_BOUNDS>
__global__ __launch_bounds__(256, 6) void attnpool_kernel(
    const float* __restrict__ h,
    const int*   __restrict__ batch,
    const float* __restrict__ W,
    const float* __restrict__ bias,
    const int*   __restrict__ seg_start,
    float*       __restrict__ out,
    int N, int B)
{
    const int tid  = threadIdx.x;
    const int wave = tid >> 6;
    const int lane = tid & 63;
    const int half = lane >> 5;            // 0: even rows, 1: odd rows
    const int col  = (lane & 31) << 2;     // this lane's 4 dims: col..col+3
    const int seg  = blockIdx.x * SEG_PER_BLOCK + wave;
    if (seg >= B) return;

    int s, e;
    if (USE_BOUNDS) {
        s = seg_start[seg];
        e = seg_start[seg + 1];
    } else {
        int lo = 0, hi = N;
        while (lo < hi) { int mid = (lo + hi) >> 1; if (batch[mid] <  seg) lo = mid + 1; else hi = mid; }
        s = lo; hi = N;
        while (lo < hi) { int mid = (lo + hi) >> 1; if (batch[mid] <= seg) lo = mid + 1; else hi = mid; }
        e = lo;
    }
    const int len = e - s;

    if (len <= 0) {
        if (half == 0) *(float4*)(out + (size_t)seg * D + col) = make_float4(0.f, 0.f, 0.f, 0.f);
        return;
    }

    const float4 w4     = *(const float4*)(W + col);
    const float  bconst = bias[0];
    const float* hbase  = h + (size_t)s * D + col;   // row r -> hbase + r*D

    float  m = -INFINITY, l = 0.f;
    float4 acc = make_float4(0.f, 0.f, 0.f, 0.f);

    auto loadChunk = [&](float4* V, int cbase) {
        #pragma unroll
        for (int i = 0; i < 4; ++i) {
            const int r = cbase + 2 * i + half;
            V[i] = (r < len) ? *(const float4*)(hbase + (size_t)r * D)
                             : make_float4(0.f, 0.f, 0.f, 0.f);
        }
    };

    auto computeChunk = [&](const float4* V, int cbase) {
        float p[4];
        #pragma unroll
        for (int i = 0; i < 4; ++i)
            p[i] = fmaf(V[i].w, w4.w, fmaf(V[i].z, w4.z, fmaf(V[i].y, w4.y, V[i].x * w4.x)));
        #pragma unroll
        for (int i = 0; i < 4; ++i) {
            #pragma unroll
            for (int o = 1; o <= 16; o <<= 1) p[i] += __shfl_xor(p[i], o);
            const int r = cbase + 2 * i + half;          // uniform per half
            p[i] = (r < len) ? (p[i] + bconst) : -INFINITY;
        }
        float lm = fmaxf(fmaxf(p[0], p[1]), fmaxf(p[2], p[3]));
        lm = fmaxf(lm, __shfl_xor(lm, 32));
        const float mnew  = fmaxf(m, lm);                // finite: >=1 valid row
        const float scale = __expf(m - mnew);            // 0 on first chunk

        float ev[4], ssum = 0.f;
        #pragma unroll
        for (int i = 0; i < 4; ++i) { ev[i] = __expf(p[i] - mnew); ssum += ev[i]; }
        const float ls = ssum + __shfl_xor(ssum, 32);

        l = fmaf(l, scale, ls);
        acc.x *= scale; acc.y *= scale; acc.z *= scale; acc.w *= scale;
        #pragma unroll
        for (int i = 0; i < 4; ++i) {
            acc.x = fmaf(ev[i], V[i].x, acc.x);
            acc.y = fmaf(ev[i], V[i].y, acc.y);
            acc.z = fmaf(ev[i], V[i].z, acc.z);
            acc.w = fmaf(ev[i], V[i].w, acc.w);
        }
        m = mnew;
    };

    float4 A[4], Bv[4];
    loadChunk(A, 0);
    int base = 0;
    for (;;) {
        loadChunk(Bv, base + 8);       // prefetch next chunk (zeros if past end)
        computeChunk(A, base);
        base += 8;
        if (base >= len) break;
        loadChunk(A, base + 8);
        computeChunk(Bv, base);
        base += 8;
        if (base >= len) break;
    }

    // combine halves (lane l and l^32 hold the same 4 dims), normalize, store
    acc.x += __shfl_xor(acc.x, 32);
    acc.y += __shfl_xor(acc.y, 32);
    acc.z += __shfl_xor(acc.z, 32);
    acc.w += __shfl_xor(acc.w, 32);
    const float inv = 1.f / l;
    acc.x *= inv; acc.y *= inv; acc.z *= inv; acc.w *= inv;
    if (half == 0) *(float4*)(out + (size_t)seg * D + col) = acc;
}

extern "C" void kernel_launch(void* const* d_in, const int* in_sizes, int n_in,
                              void* d_out, int out_size, void* d_ws, size_t ws_size,
                              hipStream_t stream) {
    const float* h     = (const float*)d_in[0];
    const int*   batch = (const int*)  d_in[1];
    const float* W     = (const float*)d_in[2];
    const float* bias  = (const float*)d_in[3];
    float*       out   = (float*)d_out;

    const int N = in_sizes[0] / D;   // 500000
    const int B = out_size / D;      // 10000

    const int grid = (B + SEG_PER_BLOCK - 1) / SEG_PER_BLOCK;

    if (ws_size >= (size_t)(B + 1) * sizeof(int)) {
        int* seg_start = (int*)d_ws;
        seg_bounds_kernel<<<(N + 255) / 256, 256, 0, stream>>>(batch, seg_start, N, B);
        attnpool_kernel<true><<<grid, 256, 0, stream>>>(h, batch, W, bias, seg_start, out, N, B);
    } else {
        attnpool_kernel<false><<<grid, 256, 0, stream>>>(h, batch, W, bias, nullptr, out, N, B);
    }
}